// Round 1
// baseline (674.761 us; speedup 1.0000x reference)
//
#include <hip/hip_runtime.h>
#include <math.h>

#define BSZ 16
#define DIMM 4096
#define NKVH 8
#define HD 128
#define SEQ 4096
#define NSPLIT 8
#define SPLITLEN 512
#define RPAD 65

// ---------------------------------------------------------------------------
// Generic skinny GEMV: out[row][b] = sum_d W[row][d] * x[b][d], 16 batches.
// 4 waves/block, 4 rows/wave (16 rows/block). x chunk (16 b x 256 d) staged in
// LDS each iteration; W rows streamed from HBM once (float4, coalesced).
// Result: res[r] valid in all lanes, for batch b = lane>>2.
// ---------------------------------------------------------------------------
__device__ __forceinline__ void gemv_rows(const float* __restrict__ xg,
                                          const float* __restrict__ W,
                                          int rbase,
                                          float* __restrict__ x_lds,
                                          float* __restrict__ rbuf,
                                          float res[4], int tid) {
  const int lane = tid & 63;
  float acc[4][16];
#pragma unroll
  for (int r = 0; r < 4; ++r)
#pragma unroll
    for (int b = 0; b < 16; ++b) acc[r][b] = 0.f;

  for (int c = 0; c < 16; ++c) {
    __syncthreads();
#pragma unroll
    for (int u = 0; u < 4; ++u) {
      int f = u * 256 + tid;      // float4 index 0..1023 (coalesced)
      int b = f >> 6;
      int dl = (f & 63) << 2;
      ((float4*)x_lds)[f] = *(const float4*)(xg + (size_t)b * DIMM + c * 256 + dl);
    }
    __syncthreads();
    float4 w4[4];
#pragma unroll
    for (int r = 0; r < 4; ++r)
      w4[r] = *(const float4*)(W + (size_t)(rbase + r) * DIMM + c * 256 + (lane << 2));
#pragma unroll
    for (int b = 0; b < 16; ++b) {
      float4 xv = ((const float4*)x_lds)[b * 64 + lane];
#pragma unroll
      for (int r = 0; r < 4; ++r) {
        acc[r][b] = fmaf(w4[r].x, xv.x, acc[r][b]);
        acc[r][b] = fmaf(w4[r].y, xv.y, acc[r][b]);
        acc[r][b] = fmaf(w4[r].z, xv.z, acc[r][b]);
        acc[r][b] = fmaf(w4[r].w, xv.w, acc[r][b]);
      }
    }
  }
  // Cross-lane reduction, per-wave LDS buffer rbuf[16][RPAD] (RPAD=65: 2-way max)
#pragma unroll
  for (int r = 0; r < 4; ++r) {
    __syncthreads();
#pragma unroll
    for (int b = 0; b < 16; ++b) rbuf[b * RPAD + lane] = acc[r][b];
    __syncthreads();
    int bb = lane >> 2, j = lane & 3;
    float s = 0.f;
#pragma unroll
    for (int k = 0; k < 16; ++k) s += rbuf[bb * RPAD + j * 16 + k];
    s += __shfl_xor(s, 1);
    s += __shfl_xor(s, 2);
    res[r] = s;  // total for batch bb, all lanes in quad agree
  }
}

// ---------------------------------------------------------------------------
// Kernel 1: QKV projection + RoPE. rows 0..4095 = wq, 4096..5119 = wk,
// 5120..6143 = wv. Block covers 16 consecutive rows (never crosses a matrix
// boundary: 4096 and 5120 are multiples of 16).
// ---------------------------------------------------------------------------
__global__ __launch_bounds__(256) void qkv_kernel(
    const float* __restrict__ x, const float* __restrict__ wq,
    const float* __restrict__ wk, const float* __restrict__ wv,
    const float* __restrict__ fcos, const float* __restrict__ fsin,
    float* __restrict__ q_ws, float* __restrict__ k_ws, float* __restrict__ v_ws) {
  __shared__ float x_lds[4096];
  __shared__ float red[4][16 * RPAD];
  const int tid = threadIdx.x;
  const int lane = tid & 63;
  const int wave = tid >> 6;
  const int row0 = blockIdx.x * 16 + wave * 4;

  const float* W;
  float* outp;
  int rbase, ostride;
  bool rope;
  if (row0 < 4096)      { W = wq; rbase = row0;        outp = q_ws; rope = true;  ostride = 4096; }
  else if (row0 < 5120) { W = wk; rbase = row0 - 4096; outp = k_ws; rope = true;  ostride = 1024; }
  else                  { W = wv; rbase = row0 - 5120; outp = v_ws; rope = false; ostride = 1024; }

  float res[4];
  gemv_rows(x, W, rbase, x_lds, red[wave], res, tid);

  if (rope) {
    int pos = rbase & 127;  // 4-aligned, pairs (r, r+1) stay within the wave
#pragma unroll
    for (int r = 0; r < 4; r += 2) {
      int i = (pos + r) >> 1;
      float c = fcos[i], s = fsin[i];
      float a = res[r], b2 = res[r + 1];
      res[r]     = a * c - b2 * s;
      res[r + 1] = a * s + b2 * c;
    }
  }
  if ((lane & 3) == 0) {
    int b = lane >> 2;
#pragma unroll
    for (int r = 0; r < 4; ++r) outp[(size_t)b * ostride + rbase + r] = res[r];
  }
}

// ---------------------------------------------------------------------------
// Kernel 2: flash-decode attention partials.
// grid (NSPLIT, NKVH, BSZ); block 256. Each block: 4 GQA q-heads, 512 keys.
// ---------------------------------------------------------------------------
__global__ __launch_bounds__(256) void attn_kernel(
    const float* __restrict__ ck, const float* __restrict__ cv,
    const float* __restrict__ q_ws, const float* __restrict__ k_new,
    const float* __restrict__ v_new, float* __restrict__ ml_ws,
    float* __restrict__ opart) {
  __shared__ float sc[SPLITLEN * 4];   // [p][h]
  __shared__ float part[16 * 128];     // [wave*4+h][d]
  const int tid = threadIdx.x, lane = tid & 63, wave = tid >> 6;
  const int split = blockIdx.x, kvh = blockIdx.y, b = blockIdx.z;
  const int p0 = split * SPLITLEN;
  const float scale = 0.08838834764831845f;  // 1/sqrt(128)

  const int dsub = (lane & 7) << 2;  // lane's 4-d offset within 32-d j-chunk
  const int prow = lane >> 3;        // 8 rows in flight per wave instr
  float4 q4[4][4];
#pragma unroll
  for (int h = 0; h < 4; ++h)
#pragma unroll
    for (int j = 0; j < 4; ++j) {
      float4 t = *(const float4*)(q_ws + (size_t)b * 4096 + (kvh * 4 + h) * 128 + j * 32 + dsub);
      q4[h][j] = make_float4(t.x * scale, t.y * scale, t.z * scale, t.w * scale);
    }

  // ---- Phase 1: scores = q . k  (8 lanes per row, shuffle reduce) ----
  for (int it = 0; it < 16; ++it) {
    int p = p0 + wave * 128 + it * 8 + prow;
    const float* kp = (p == 4095) ? (k_new + (size_t)(b * 8 + kvh) * 128)
                                  : (ck + ((size_t)(b * 4096 + p) * 8 + kvh) * 128);
    float s0 = 0, s1 = 0, s2 = 0, s3 = 0;
#pragma unroll
    for (int j = 0; j < 4; ++j) {
      float4 k4 = *(const float4*)(kp + j * 32 + dsub);
      s0 = fmaf(k4.x, q4[0][j].x, s0); s0 = fmaf(k4.y, q4[0][j].y, s0);
      s0 = fmaf(k4.z, q4[0][j].z, s0); s0 = fmaf(k4.w, q4[0][j].w, s0);
      s1 = fmaf(k4.x, q4[1][j].x, s1); s1 = fmaf(k4.y, q4[1][j].y, s1);
      s1 = fmaf(k4.z, q4[1][j].z, s1); s1 = fmaf(k4.w, q4[1][j].w, s1);
      s2 = fmaf(k4.x, q4[2][j].x, s2); s2 = fmaf(k4.y, q4[2][j].y, s2);
      s2 = fmaf(k4.z, q4[2][j].z, s2); s2 = fmaf(k4.w, q4[2][j].w, s2);
      s3 = fmaf(k4.x, q4[3][j].x, s3); s3 = fmaf(k4.y, q4[3][j].y, s3);
      s3 = fmaf(k4.z, q4[3][j].z, s3); s3 = fmaf(k4.w, q4[3][j].w, s3);
    }
#pragma unroll
    for (int m = 1; m <= 4; m <<= 1) {
      s0 += __shfl_xor(s0, m); s1 += __shfl_xor(s1, m);
      s2 += __shfl_xor(s2, m); s3 += __shfl_xor(s3, m);
    }
    if ((lane & 7) == 0)
      ((float4*)sc)[wave * 128 + it * 8 + prow] = make_float4(s0, s1, s2, s3);
  }
  __syncthreads();

  // ---- Phase 1.5: per-split softmax (wave w handles head w) ----
  {
    int h = wave;
    float vals[8];
    float m = -1e30f;
#pragma unroll
    for (int k = 0; k < 8; ++k) {
      vals[k] = sc[(k * 64 + lane) * 4 + h];
      m = fmaxf(m, vals[k]);
    }
#pragma unroll
    for (int mk = 1; mk <= 32; mk <<= 1) m = fmaxf(m, __shfl_xor(m, mk));
    float lsum = 0;
#pragma unroll
    for (int k = 0; k < 8; ++k) {
      float e = __expf(vals[k] - m);
      sc[(k * 64 + lane) * 4 + h] = e;
      lsum += e;
    }
#pragma unroll
    for (int mk = 1; mk <= 32; mk <<= 1) lsum += __shfl_xor(lsum, mk);
    if (lane == 0) {
      int hg = kvh * 4 + h;
      ml_ws[((size_t)(b * 32 + hg) * NSPLIT + split) * 2 + 0] = m;
      ml_ws[((size_t)(b * 32 + hg) * NSPLIT + split) * 2 + 1] = lsum;
    }
  }
  __syncthreads();

  // ---- Phase 2: PV (wave w handles p-quarter w; each V row read once) ----
  {
    int d0 = lane * 2;
    float a00 = 0, a01 = 0, a10 = 0, a11 = 0, a20 = 0, a21 = 0, a30 = 0, a31 = 0;
    for (int k = 0; k < 128; ++k) {
      int pl = wave * 128 + k;
      int p = p0 + pl;
      const float* vp = (p == 4095) ? (v_new + (size_t)(b * 8 + kvh) * 128)
                                    : (cv + ((size_t)(b * 4096 + p) * 8 + kvh) * 128);
      float2 v2 = *(const float2*)(vp + d0);
      float4 s4 = ((const float4*)sc)[pl];  // broadcast
      a00 = fmaf(s4.x, v2.x, a00); a01 = fmaf(s4.x, v2.y, a01);
      a10 = fmaf(s4.y, v2.x, a10); a11 = fmaf(s4.y, v2.y, a11);
      a20 = fmaf(s4.z, v2.x, a20); a21 = fmaf(s4.z, v2.y, a21);
      a30 = fmaf(s4.w, v2.x, a30); a31 = fmaf(s4.w, v2.y, a31);
    }
    *(float2*)&part[(wave * 4 + 0) * 128 + d0] = make_float2(a00, a01);
    *(float2*)&part[(wave * 4 + 1) * 128 + d0] = make_float2(a10, a11);
    *(float2*)&part[(wave * 4 + 2) * 128 + d0] = make_float2(a20, a21);
    *(float2*)&part[(wave * 4 + 3) * 128 + d0] = make_float2(a30, a31);
  }
  __syncthreads();
  {
    int hh = tid >> 6, dd = (tid & 63) * 2;
    float o0 = 0, o1 = 0;
#pragma unroll
    for (int w = 0; w < 4; ++w) {
      o0 += part[(w * 4 + hh) * 128 + dd];
      o1 += part[(w * 4 + hh) * 128 + dd + 1];
    }
    int hg = kvh * 4 + hh;
    size_t base = ((size_t)(b * 32 + hg) * NSPLIT + split) * 128;
    *(float2*)(opart + base + dd) = make_float2(o0, o1);
  }
}

// ---------------------------------------------------------------------------
// Kernel 3: combine split partials (flash rescale).
// ---------------------------------------------------------------------------
__global__ __launch_bounds__(128) void combine_kernel(
    const float* __restrict__ ml_ws, const float* __restrict__ opart,
    float* __restrict__ attn_ws) {
  int bh = blockIdx.x;  // b*32 + h
  int d = threadIdx.x;
  float mv[NSPLIT], lv[NSPLIT];
  float M = -1e30f;
#pragma unroll
  for (int i = 0; i < NSPLIT; ++i) {
    mv[i] = ml_ws[((size_t)bh * NSPLIT + i) * 2];
    lv[i] = ml_ws[((size_t)bh * NSPLIT + i) * 2 + 1];
    M = fmaxf(M, mv[i]);
  }
  float L = 0, o = 0;
#pragma unroll
  for (int i = 0; i < NSPLIT; ++i) {
    float w = __expf(mv[i] - M);
    L += w * lv[i];
    o += w * opart[((size_t)bh * NSPLIT + i) * 128 + d];
  }
  attn_ws[(size_t)bh * 128 + d] = o / L;
}

// ---------------------------------------------------------------------------
// Kernel 4: output projection with wo.
// ---------------------------------------------------------------------------
__global__ __launch_bounds__(256) void oproj_kernel(
    const float* __restrict__ xin, const float* __restrict__ wo,
    float* __restrict__ out) {
  __shared__ float x_lds[4096];
  __shared__ float red[4][16 * RPAD];
  const int tid = threadIdx.x;
  const int lane = tid & 63;
  const int wave = tid >> 6;
  const int row0 = blockIdx.x * 16 + wave * 4;
  float res[4];
  gemv_rows(xin, wo, row0, x_lds, red[wave], res, tid);
  if ((lane & 3) == 0) {
    int b = lane >> 2;
#pragma unroll
    for (int r = 0; r < 4; ++r) out[(size_t)b * 4096 + row0 + r] = res[r];
  }
}

extern "C" void kernel_launch(void* const* d_in, const int* in_sizes, int n_in,
                              void* d_out, int out_size, void* d_ws, size_t ws_size,
                              hipStream_t stream) {
  const float* x  = (const float*)d_in[0];
  const float* wq = (const float*)d_in[1];
  const float* wk = (const float*)d_in[2];
  const float* wv = (const float*)d_in[3];
  const float* wo = (const float*)d_in[4];
  const float* ck = (const float*)d_in[5];
  const float* cv = (const float*)d_in[6];
  const float* fc = (const float*)d_in[7];
  const float* fs = (const float*)d_in[8];

  float* ws      = (float*)d_ws;
  float* q_ws    = ws;               // 16*4096          = 65536
  float* k_ws    = q_ws + 65536;     // 16*1024          = 16384
  float* v_ws    = k_ws + 16384;     // 16*1024          = 16384
  float* ml_ws   = v_ws + 16384;     // 16*32*8*2        = 8192
  float* opart   = ml_ws + 8192;     // 16*32*8*128      = 524288
  float* attn_ws = opart + 524288;   // 16*4096          = 65536
  // total ~2.79 MB of workspace

  qkv_kernel<<<384, 256, 0, stream>>>(x, wq, wk, wv, fc, fs, q_ws, k_ws, v_ws);
  attn_kernel<<<dim3(NSPLIT, NKVH, BSZ), 256, 0, stream>>>(ck, cv, q_ws, k_ws, v_ws,
                                                           ml_ws, opart);
  combine_kernel<<<BSZ * 32, 128, 0, stream>>>(ml_ws, opart, attn_ws);
  oproj_kernel<<<256, 256, 0, stream>>>(attn_ws, wo, (float*)d_out);
}

// Round 2
// 661.471 us; speedup vs baseline: 1.0201x; 1.0201x over previous
//
#include <hip/hip_runtime.h>
#include <math.h>

#define BSZ 16
#define DIMM 4096
#define NKVH 8
#define HD 128
#define SEQ 4096
#define NSPLIT 16
#define SPLITLEN 256
#define RPAD 65

// ---------------------------------------------------------------------------
// Skinny GEMV: out[row][b] = sum_d W[row][d] * x[b][d], 16 batches.
// 4 waves/block, 2 rows/wave (8 rows/block). x chunk (16 b x 256 d) staged in
// LDS per iteration; W rows streamed from HBM once (float4, coalesced).
// res[r] valid in all lanes, for batch b = lane>>2.
// ---------------------------------------------------------------------------
__device__ __forceinline__ void gemv_rows2(const float* __restrict__ xg,
                                           const float* __restrict__ W,
                                           int rbase,
                                           float* __restrict__ x_lds,
                                           float* __restrict__ rbuf,
                                           float res[2], int tid) {
  const int lane = tid & 63;
  float acc[2][16];
#pragma unroll
  for (int r = 0; r < 2; ++r)
#pragma unroll
    for (int b = 0; b < 16; ++b) acc[r][b] = 0.f;

  for (int c = 0; c < 16; ++c) {
    __syncthreads();
#pragma unroll
    for (int u = 0; u < 4; ++u) {
      int f = u * 256 + tid;      // float4 index 0..1023 (coalesced)
      int b = f >> 6;
      int dl = (f & 63) << 2;
      ((float4*)x_lds)[f] = *(const float4*)(xg + (size_t)b * DIMM + c * 256 + dl);
    }
    __syncthreads();
    float4 w4[2];
#pragma unroll
    for (int r = 0; r < 2; ++r)
      w4[r] = *(const float4*)(W + (size_t)(rbase + r) * DIMM + c * 256 + (lane << 2));
#pragma unroll
    for (int b = 0; b < 16; ++b) {
      float4 xv = ((const float4*)x_lds)[b * 64 + lane];
#pragma unroll
      for (int r = 0; r < 2; ++r) {
        acc[r][b] = fmaf(w4[r].x, xv.x, acc[r][b]);
        acc[r][b] = fmaf(w4[r].y, xv.y, acc[r][b]);
        acc[r][b] = fmaf(w4[r].z, xv.z, acc[r][b]);
        acc[r][b] = fmaf(w4[r].w, xv.w, acc[r][b]);
      }
    }
  }
#pragma unroll
  for (int r = 0; r < 2; ++r) {
    __syncthreads();
#pragma unroll
    for (int b = 0; b < 16; ++b) rbuf[b * RPAD + lane] = acc[r][b];
    __syncthreads();
    int bb = lane >> 2, j = lane & 3;
    float s = 0.f;
#pragma unroll
    for (int k = 0; k < 16; ++k) s += rbuf[bb * RPAD + j * 16 + k];
    s += __shfl_xor(s, 1);
    s += __shfl_xor(s, 2);
    res[r] = s;
  }
}

// ---------------------------------------------------------------------------
// Kernel 1: QKV projection + RoPE + in-place KV-cache update at pos 4095.
// rows 0..4095 = wq, 4096..5119 = wk, 5120..6143 = wv. 8 rows/block.
// ---------------------------------------------------------------------------
__global__ __launch_bounds__(256) void qkv_kernel(
    const float* __restrict__ x, const float* __restrict__ wq,
    const float* __restrict__ wk, const float* __restrict__ wv,
    const float* __restrict__ fcos, const float* __restrict__ fsin,
    float* __restrict__ q_ws, float* __restrict__ ckw, float* __restrict__ cvw) {
  __shared__ float x_lds[4096];
  __shared__ float red[4][16 * RPAD];
  const int tid = threadIdx.x;
  const int lane = tid & 63;
  const int wave = tid >> 6;
  const int row0 = blockIdx.x * 8 + wave * 2;

  const float* W;
  int rbase, kind;  // 0=q, 1=k, 2=v
  if (row0 < 4096)      { W = wq; rbase = row0;        kind = 0; }
  else if (row0 < 5120) { W = wk; rbase = row0 - 4096; kind = 1; }
  else                  { W = wv; rbase = row0 - 5120; kind = 2; }

  float res[2];
  gemv_rows2(x, W, rbase, x_lds, red[wave], res, tid);

  if (kind <= 1) {  // RoPE: rows (rbase, rbase+1) are one even/odd pair
    int i = (rbase & 127) >> 1;
    float c = fcos[i], s = fsin[i];
    float a = res[0], b2 = res[1];
    res[0] = a * c - b2 * s;
    res[1] = a * s + b2 * c;
  }
  if ((lane & 3) == 0) {
    int b = lane >> 2;
    if (kind == 0) {
#pragma unroll
      for (int r = 0; r < 2; ++r) q_ws[(size_t)b * 4096 + rbase + r] = res[r];
    } else {
      int kvh = rbase >> 7, dpos = rbase & 127;
      float* dst = (kind == 1) ? ckw : cvw;
#pragma unroll
      for (int r = 0; r < 2; ++r)
        dst[((size_t)(b * 4096 + 4095) * 8 + kvh) * 128 + dpos + r] = res[r];
    }
  }
}

// ---------------------------------------------------------------------------
// Kernel 2: flash-decode attention partials. Cache rows only (pos 4095 was
// updated in-place by qkv_kernel) -> branchless streaming loops.
// grid (NSPLIT, NKVH, BSZ); block 256. 4 GQA q-heads, 256 keys per block.
// ---------------------------------------------------------------------------
__global__ __launch_bounds__(256) void attn_kernel(
    const float* __restrict__ ck, const float* __restrict__ cv,
    const float* __restrict__ q_ws, float* __restrict__ ml_ws,
    float* __restrict__ opart) {
  __shared__ float sc[SPLITLEN * 4];   // [p][h]
  __shared__ float part[32 * 128];     // [half*16 + wave*4 + h][d]
  const int tid = threadIdx.x, lane = tid & 63, wave = tid >> 6;
  const int split = blockIdx.x, kvh = blockIdx.y, b = blockIdx.z;
  const int p0 = split * SPLITLEN;
  const float scale = 0.08838834764831845f;  // 1/sqrt(128)

  // ---- Phase 1: scores = q . k  (8 lanes per row, shuffle reduce) ----
  {
    const int dsub = (lane & 7) << 2;
    const int prow = lane >> 3;
    float4 q4[4][4];
#pragma unroll
    for (int h = 0; h < 4; ++h)
#pragma unroll
      for (int j = 0; j < 4; ++j) {
        float4 t = *(const float4*)(q_ws + (size_t)b * 4096 + (kvh * 4 + h) * 128 + j * 32 + dsub);
        q4[h][j] = make_float4(t.x * scale, t.y * scale, t.z * scale, t.w * scale);
      }
#pragma unroll 2
    for (int it = 0; it < 8; ++it) {
      int pl = wave * 64 + it * 8 + prow;
      const float* kp = ck + ((size_t)(b * 4096 + p0 + pl) * 8 + kvh) * 128;
      float s0 = 0, s1 = 0, s2 = 0, s3 = 0;
#pragma unroll
      for (int j = 0; j < 4; ++j) {
        float4 k4 = *(const float4*)(kp + j * 32 + dsub);
        s0 = fmaf(k4.x, q4[0][j].x, s0); s0 = fmaf(k4.y, q4[0][j].y, s0);
        s0 = fmaf(k4.z, q4[0][j].z, s0); s0 = fmaf(k4.w, q4[0][j].w, s0);
        s1 = fmaf(k4.x, q4[1][j].x, s1); s1 = fmaf(k4.y, q4[1][j].y, s1);
        s1 = fmaf(k4.z, q4[1][j].z, s1); s1 = fmaf(k4.w, q4[1][j].w, s1);
        s2 = fmaf(k4.x, q4[2][j].x, s2); s2 = fmaf(k4.y, q4[2][j].y, s2);
        s2 = fmaf(k4.z, q4[2][j].z, s2); s2 = fmaf(k4.w, q4[2][j].w, s2);
        s3 = fmaf(k4.x, q4[3][j].x, s3); s3 = fmaf(k4.y, q4[3][j].y, s3);
        s3 = fmaf(k4.z, q4[3][j].z, s3); s3 = fmaf(k4.w, q4[3][j].w, s3);
      }
#pragma unroll
      for (int m = 1; m <= 4; m <<= 1) {
        s0 += __shfl_xor(s0, m); s1 += __shfl_xor(s1, m);
        s2 += __shfl_xor(s2, m); s3 += __shfl_xor(s3, m);
      }
      if ((lane & 7) == 0)
        ((float4*)sc)[pl] = make_float4(s0, s1, s2, s3);
    }
  }
  __syncthreads();

  // ---- Phase 1.5: per-split softmax (wave w handles head w) ----
  {
    int h = wave;
    float vals[4];
    float m = -1e30f;
#pragma unroll
    for (int k = 0; k < 4; ++k) {
      vals[k] = sc[(k * 64 + lane) * 4 + h];
      m = fmaxf(m, vals[k]);
    }
#pragma unroll
    for (int mk = 1; mk <= 32; mk <<= 1) m = fmaxf(m, __shfl_xor(m, mk));
    float lsum = 0;
#pragma unroll
    for (int k = 0; k < 4; ++k) {
      float e = __expf(vals[k] - m);
      sc[(k * 64 + lane) * 4 + h] = e;
      lsum += e;
    }
#pragma unroll
    for (int mk = 1; mk <= 32; mk <<= 1) lsum += __shfl_xor(lsum, mk);
    if (lane == 0) {
      int hg = kvh * 4 + h;
      ml_ws[((size_t)(b * 32 + hg) * NSPLIT + split) * 2 + 0] = m;
      ml_ws[((size_t)(b * 32 + hg) * NSPLIT + split) * 2 + 1] = lsum;
    }
  }
  __syncthreads();

  // ---- Phase 2: PV. 2 rows/iter (half-wave each), float4 loads ----
  {
    const int dq = lane & 31;     // float4 column index: d = dq*4
    const int half = lane >> 5;
    float4 a0 = {0,0,0,0}, a1 = {0,0,0,0}, a2 = {0,0,0,0}, a3 = {0,0,0,0};
#pragma unroll 4
    for (int it = 0; it < 32; ++it) {
      int pl = wave * 64 + it * 2 + half;
      const float* vp = cv + ((size_t)(b * 4096 + p0 + pl) * 8 + kvh) * 128;
      float4 v4 = *(const float4*)(vp + dq * 4);
      float4 s4 = ((const float4*)sc)[pl];  // 2-way LDS broadcast
      a0.x = fmaf(s4.x, v4.x, a0.x); a0.y = fmaf(s4.x, v4.y, a0.y);
      a0.z = fmaf(s4.x, v4.z, a0.z); a0.w = fmaf(s4.x, v4.w, a0.w);
      a1.x = fmaf(s4.y, v4.x, a1.x); a1.y = fmaf(s4.y, v4.y, a1.y);
      a1.z = fmaf(s4.y, v4.z, a1.z); a1.w = fmaf(s4.y, v4.w, a1.w);
      a2.x = fmaf(s4.z, v4.x, a2.x); a2.y = fmaf(s4.z, v4.y, a2.y);
      a2.z = fmaf(s4.z, v4.z, a2.z); a2.w = fmaf(s4.z, v4.w, a2.w);
      a3.x = fmaf(s4.w, v4.x, a3.x); a3.y = fmaf(s4.w, v4.y, a3.y);
      a3.z = fmaf(s4.w, v4.z, a3.z); a3.w = fmaf(s4.w, v4.w, a3.w);
    }
    int rb = (half * 16 + wave * 4) * 128 + dq * 4;
    *(float4*)&part[rb + 0 * 128] = a0;
    *(float4*)&part[rb + 1 * 128] = a1;
    *(float4*)&part[rb + 2 * 128] = a2;
    *(float4*)&part[rb + 3 * 128] = a3;
  }
  __syncthreads();
  {
    int hh = tid >> 6, dd = (tid & 63) * 2;
    float o0 = 0, o1 = 0;
#pragma unroll
    for (int g = 0; g < 8; ++g) {
      int row = (g >> 2) * 16 + (g & 3) * 4 + hh;
      float2 p2 = *(const float2*)&part[row * 128 + dd];
      o0 += p2.x; o1 += p2.y;
    }
    int hg = kvh * 4 + hh;
    size_t base = ((size_t)(b * 32 + hg) * NSPLIT + split) * 128;
    *(float2*)(opart + base + dd) = make_float2(o0, o1);
  }
}

// ---------------------------------------------------------------------------
// Kernel 3: combine split partials (flash rescale).
// ---------------------------------------------------------------------------
__global__ __launch_bounds__(128) void combine_kernel(
    const float* __restrict__ ml_ws, const float* __restrict__ opart,
    float* __restrict__ attn_ws) {
  int bh = blockIdx.x;  // b*32 + h
  int d = threadIdx.x;
  float mv[NSPLIT], lv[NSPLIT];
  float M = -1e30f;
#pragma unroll
  for (int i = 0; i < NSPLIT; ++i) {
    mv[i] = ml_ws[((size_t)bh * NSPLIT + i) * 2];
    lv[i] = ml_ws[((size_t)bh * NSPLIT + i) * 2 + 1];
    M = fmaxf(M, mv[i]);
  }
  float L = 0, o = 0;
#pragma unroll
  for (int i = 0; i < NSPLIT; ++i) {
    float w = __expf(mv[i] - M);
    L += w * lv[i];
    o += w * opart[((size_t)bh * NSPLIT + i) * 128 + d];
  }
  attn_ws[(size_t)bh * 128 + d] = o / L;
}

// ---------------------------------------------------------------------------
// Kernel 4: output projection with wo. 8 rows/block.
// ---------------------------------------------------------------------------
__global__ __launch_bounds__(256) void oproj_kernel(
    const float* __restrict__ xin, const float* __restrict__ wo,
    float* __restrict__ out) {
  __shared__ float x_lds[4096];
  __shared__ float red[4][16 * RPAD];
  const int tid = threadIdx.x;
  const int lane = tid & 63;
  const int wave = tid >> 6;
  const int row0 = blockIdx.x * 8 + wave * 2;
  float res[2];
  gemv_rows2(xin, wo, row0, x_lds, red[wave], res, tid);
  if ((lane & 3) == 0) {
    int b = lane >> 2;
#pragma unroll
    for (int r = 0; r < 2; ++r) out[(size_t)b * 4096 + row0 + r] = res[r];
  }
}

extern "C" void kernel_launch(void* const* d_in, const int* in_sizes, int n_in,
                              void* d_out, int out_size, void* d_ws, size_t ws_size,
                              hipStream_t stream) {
  const float* x  = (const float*)d_in[0];
  const float* wq = (const float*)d_in[1];
  const float* wk = (const float*)d_in[2];
  const float* wv = (const float*)d_in[3];
  const float* wo = (const float*)d_in[4];
  float* ck = (float*)d_in[5];   // mutated in place at pos 4095 (idempotent;
  float* cv = (float*)d_in[6];   // harness restores inputs before each replay)
  const float* fc = (const float*)d_in[7];
  const float* fs = (const float*)d_in[8];

  float* ws      = (float*)d_ws;
  float* q_ws    = ws;               // 16*4096            = 65536
  float* ml_ws   = q_ws + 65536;     // 16*32*16*2         = 16384
  float* opart   = ml_ws + 16384;    // 16*32*16*128       = 1048576
  float* attn_ws = opart + 1048576;  // 16*4096            = 65536
  // total ~4.8 MB of workspace

  qkv_kernel<<<768, 256, 0, stream>>>(x, wq, wk, wv, fc, fs, q_ws, ck, cv);
  attn_kernel<<<dim3(NSPLIT, NKVH, BSZ), 256, 0, stream>>>(ck, cv, q_ws, ml_ws, opart);
  combine_kernel<<<BSZ * 32, 128, 0, stream>>>(ml_ws, opart, attn_ws);
  oproj_kernel<<<512, 256, 0, stream>>>(attn_ws, wo, (float*)d_out);
}